// Round 1
// baseline (20818.288 us; speedup 1.0000x reference)
//
#include <hip/hip_runtime.h>
#include <math.h>

#define B8 8

static __device__ __forceinline__ float sigmoidf_(float x){ return 1.f/(1.f+expf(-x)); }

// ---------------- gray ----------------
__global__ void k_gray(const float* __restrict__ rgb, float* __restrict__ gray, int B){
  const int HW = 512*512;
  int idx = blockIdx.x*256 + threadIdx.x;
  if (idx >= B*HW) return;
  int b = idx / HW, i = idx % HW;
  const float* p = rgb + (size_t)b*3*HW;
  float v = 0.299f*p[i] + 0.587f*p[i+HW] + 0.114f*p[i+2*HW];
  v *= 255.f;
  v = fminf(fmaxf(v, 0.f), 255.f);
  gray[idx] = v;
}

// ---------------- blur flags (var of laplacian over 8x8 win, stride 4) ----------------
__global__ void k_flags(const float* __restrict__ gray, float* __restrict__ flags, int B){
  const int NW = 127*127;
  int idx = blockIdx.x*256 + threadIdx.x;
  if (idx >= B*NW) return;
  int b = idx/NW, r = idx%NW;
  int wy = r/127, wx = r%127;
  const float* g = gray + (size_t)b*512*512;
  float s1 = 0.f, s2 = 0.f;
  for (int iy=0; iy<8; ++iy){
    int y = 4*wy + iy;
    for (int ix=0; ix<8; ++ix){
      int x = 4*wx + ix;
      float c  = g[y*512+x];
      float up = (y>0)   ? g[(y-1)*512+x] : 0.f;
      float dn = (y<511) ? g[(y+1)*512+x] : 0.f;
      float lf = (x>0)   ? g[y*512+x-1]   : 0.f;
      float rt = (x<511) ? g[y*512+x+1]   : 0.f;
      float lap = up+dn+lf+rt - 4.f*c;
      s1 += lap; s2 += lap*lap;
    }
  }
  float var = (s2 - s1*s1*(1.f/64.f)) * (1.f/63.f);
  flags[idx] = (var < 50.f) ? 1.f : 0.f;
}

// ---------------- downsampled masks (rgb from flags OR, depth from z<=0) ----------------
__global__ void k_masks(const float* __restrict__ flags, const float* __restrict__ depth,
                        float* __restrict__ ri, float* __restrict__ di,
                        int B, int h, int st){
  int n = B*h*h;
  int idx = blockIdx.x*256 + threadIdx.x;
  if (idx >= n) return;
  int b = idx/(h*h), i = idx%(h*h);
  int y = (i/h)*st, x = (i%h)*st;
  const float* f = flags + (size_t)b*127*127;
  int fy = y>>2, fx = x>>2;
  float v = f[fy*127+fx];
  if (y>0)         v = fmaxf(v, f[(fy-1)*127+fx]);
  if (x>0)         v = fmaxf(v, f[fy*127+fx-1]);
  if (y>0 && x>0)  v = fmaxf(v, f[(fy-1)*127+fx-1]);
  ri[idx] = v;
  const int IHW = 512*512;
  di[idx] = (depth[(size_t)b*3*IHW + 2*IHW + (size_t)y*512 + x] <= 0.f) ? 1.f : 0.f;
}

// ---------------- 3x3 same-pad conv, fp32, LDS-tiled, 4-wide x-microtile ----------------
template<int TH, int TW>
__global__ __launch_bounds__(TH*(TW/4))
void k_conv3x3(const float* __restrict__ in, const float* __restrict__ wgt,
               float* __restrict__ out, int B, int C, int H, int W){
  constexpr int NTH = TH*(TW/4);
  constexpr int RW  = ((TW+2+3) & ~3);     // 16B-aligned LDS rows
  __shared__ __align__(16) float s_in[4][TH+2][RW];
  int co = blockIdx.y;
  int tilesX = W/TW, tilesY = H/TH;
  int bt = blockIdx.x;
  int tX = bt % tilesX; int tmp = bt / tilesX;
  int tY = tmp % tilesY; int b = tmp / tilesY;
  int y0 = tY*TH, x0 = tX*TW;
  int lane = threadIdx.x;
  int ly  = lane / (TW/4);
  int lx0 = (lane % (TW/4))*4;
  float acc0=0.f, acc1=0.f, acc2=0.f, acc3=0.f;
  const float* inb   = in  + (size_t)b*C*H*W;
  const float* wbase = wgt + (size_t)co*C*9;

  for (int ci0 = 0; ci0 < C; ci0 += 4){
    float wq[36];
    #pragma unroll
    for (int k=0;k<36;++k) wq[k] = wbase[(size_t)ci0*9 + k];
    // stage 4 input channel tiles (with halo, zero-pad OOB)
    for (int idx = lane; idx < 4*(TH+2)*(TW+2); idx += NTH){
      int q   = idx / ((TH+2)*(TW+2));
      int rem = idx % ((TH+2)*(TW+2));
      int iy = rem / (TW+2), ix = rem % (TW+2);
      int gy = y0+iy-1, gx = x0+ix-1;
      float v = 0.f;
      if (gy>=0 && gy<H && gx>=0 && gx<W)
        v = inb[(size_t)(ci0+q)*H*W + (size_t)gy*W + gx];
      s_in[q][iy][ix] = v;
    }
    __syncthreads();
    #pragma unroll
    for (int q=0;q<4;++q){
      #pragma unroll
      for (int ky=0;ky<3;++ky){
        float4 v4 = *(const float4*)&s_in[q][ly+ky][lx0];
        float2 v2 = *(const float2*)&s_in[q][ly+ky][lx0+4];
        float r0=v4.x, r1=v4.y, r2=v4.z, r3=v4.w, r4=v2.x, r5=v2.y;
        float w0=wq[q*9+ky*3+0], w1=wq[q*9+ky*3+1], w2=wq[q*9+ky*3+2];
        acc0 += w0*r0 + w1*r1 + w2*r2;
        acc1 += w0*r1 + w1*r2 + w2*r3;
        acc2 += w0*r2 + w1*r3 + w2*r4;
        acc3 += w0*r3 + w1*r4 + w2*r5;
      }
    }
    __syncthreads();
  }
  float4 o; o.x=acc0; o.y=acc1; o.z=acc2; o.w=acc3;
  *(float4*)&out[((size_t)b*C+co)*H*W + (size_t)(y0+ly)*W + x0+lx0] = o;
}

// ---------------- BN batch-stats -> per-channel alpha/beta ----------------
__global__ void k_bnstats(const float* __restrict__ conv, const float* __restrict__ g,
                          const float* __restrict__ bb, float* __restrict__ alpha,
                          float* __restrict__ beta, int B, int C, int HW){
  int c = blockIdx.x;
  int tid = threadIdx.x;
  float s1=0.f, s2=0.f;
  for (int b=0;b<B;++b){
    const float* p = conv + ((size_t)b*C + c)*HW;
    for (int i=tid;i<HW;i+=256){ float v=p[i]; s1+=v; s2+=v*v; }
  }
  __shared__ float sb1[4], sb2[4];
  #pragma unroll
  for (int off=32; off; off>>=1){ s1 += __shfl_down(s1,off); s2 += __shfl_down(s2,off); }
  int wid = tid>>6;
  if ((tid&63)==0){ sb1[wid]=s1; sb2[wid]=s2; }
  __syncthreads();
  if (tid==0){
    s1 = sb1[0]+sb1[1]+sb1[2]+sb1[3];
    s2 = sb2[0]+sb2[1]+sb2[2]+sb2[3];
    float N = (float)(B*HW);
    float mean = s1/N;
    float var  = s2/N - mean*mean;
    float a = g[c] / sqrtf(var + 1e-5f);
    alpha[c] = a;
    beta[c]  = bb[c] - mean*a;
  }
}

// ---------------- per-position channel mean/max ----------------
template<int NS>
__global__ void k_spstats(const float* __restrict__ main_, float* __restrict__ spmean,
                          float* __restrict__ spmax, int B, int C, int HW){
  constexpr int PPB = 256/NS;
  int tid = threadIdx.x;
  int slice = tid % NS;
  int pos = blockIdx.x*PPB + tid/NS;      // exact grids; no guard needed
  int b = pos / HW, i = pos % HW;
  const float* p = main_ + (size_t)b*C*HW + i;
  float sum = 0.f, mx = -INFINITY;
  for (int c=slice; c<C; c+=NS){
    float v = p[(size_t)c*HW];
    sum += v; mx = fmaxf(mx, v);
  }
  #pragma unroll
  for (int off=NS/2; off; off>>=1){
    sum += __shfl_xor(sum, off);
    mx = fmaxf(mx, __shfl_xor(mx, off));
  }
  if (slice==0){ spmean[pos] = sum/C; spmax[pos] = mx; }
}

// ---------------- spatial attention: sigmoid(conv7x7([mean,max,xs,ys])) ----------------
__global__ void k_sw(const float* __restrict__ spmean, const float* __restrict__ spmax,
                     const float* __restrict__ sa, float* __restrict__ sw,
                     int B, int H, int W){
  __shared__ float s_sa[196];
  int tid = threadIdx.x;
  if (tid < 196) s_sa[tid] = sa[tid];
  __syncthreads();
  int HW = H*W;
  int gpos = blockIdx.x*256 + tid;
  if (gpos >= B*HW) return;
  int b = gpos/HW, i = gpos%HW;
  int y = i/W, x = i%W;
  float inv_w = 2.f/(float)(W-1), inv_h = 2.f/(float)(H-1);
  const float* pm = spmean + (size_t)b*HW;
  const float* px = spmax  + (size_t)b*HW;
  float acc = 0.f;
  for (int ky=0;ky<7;++ky){
    int yy = y+ky-3;
    if (yy<0 || yy>=H) continue;
    float ysv = -1.f + yy*inv_h;
    for (int kx=0;kx<7;++kx){
      int xx = x+kx-3;
      if (xx<0 || xx>=W) continue;
      float xsv = -1.f + xx*inv_w;
      int kk = ky*7+kx;
      acc += s_sa[kk]*pm[yy*W+xx] + s_sa[49+kk]*px[yy*W+xx]
           + s_sa[98+kk]*xsv + s_sa[147+kk]*ysv;
    }
  }
  sw[gpos] = sigmoidf_(acc);
}

// ---------------- global average pool per (b,c) ----------------
__global__ void k_gap(const float* __restrict__ main_, float* __restrict__ gap,
                      int C, int HW){
  const float* p = main_ + (size_t)blockIdx.x*HW;
  float s = 0.f;
  for (int i=threadIdx.x; i<HW; i+=64) s += p[i];
  #pragma unroll
  for (int off=32; off; off>>=1) s += __shfl_down(s, off);
  if (threadIdx.x==0) gap[blockIdx.x] = s/(float)HW;
}

// ---------------- channel attention MLP ----------------
__global__ void k_mlp(const float* __restrict__ gap, const float* __restrict__ w1,
                      const float* __restrict__ w2, float* __restrict__ cw,
                      int C, int R){
  int b = blockIdx.x;
  __shared__ float sh[64];
  const float* gp = gap + (size_t)b*C;
  int tid = threadIdx.x;
  if (tid < R){
    float s = 0.f;
    for (int c2=0;c2<C;++c2) s += w1[(size_t)tid*C + c2]*gp[c2];
    sh[tid] = fmaxf(s, 0.f);
  }
  __syncthreads();
  for (int c2=tid; c2<C; c2+=256){
    float s = 0.f;
    for (int r=0;r<R;++r) s += w2[(size_t)c2*R + r]*sh[r];
    cw[(size_t)b*C + c2] = sigmoidf_(s);
  }
}

// ---------------- final masked compose ----------------
__global__ void k_final(const float* __restrict__ main_, const float* __restrict__ conv,
                        const float* __restrict__ alpha, const float* __restrict__ beta,
                        const float* __restrict__ sw, const float* __restrict__ cw,
                        const float* __restrict__ mask, float* __restrict__ out,
                        int B, int C, int HW){
  size_t idx = (size_t)blockIdx.x*256 + threadIdx.x;
  size_t N = (size_t)B*C*HW;
  if (idx >= N) return;
  int i = (int)(idx % HW);
  size_t t = idx / HW;
  int c = (int)(t % C);
  int b = (int)(t / C);
  float m = mask[(size_t)b*HW + i];
  float res;
  if (m > 0.5f){
    float at = fmaxf(alpha[c]*conv[idx] + beta[c], 0.f);
    res = 2.f*at*sw[(size_t)b*HW + i]*cw[(size_t)b*C + c];
  } else {
    res = main_[idx];
  }
  out[idx] = res;
}

extern "C" void kernel_launch(void* const* d_in, const int* in_sizes, int n_in,
                              void* d_out, int out_size, void* d_ws, size_t ws_size,
                              hipStream_t stream){
  (void)in_sizes; (void)n_in; (void)out_size; (void)ws_size;
  const int B = B8;
  const float* rgb_feat[3] = {(const float*)d_in[0], (const float*)d_in[2], (const float*)d_in[4]};
  const float* dep_feat[3] = {(const float*)d_in[1], (const float*)d_in[3], (const float*)d_in[5]};
  const float* rgb_img = (const float*)d_in[6];
  const float* dep_img = (const float*)d_in[7];

  const int Cs[3]  = {256, 512, 1024};
  const int hs[3]  = {64, 32, 16};
  const int sts[3] = {8, 16, 32};
  const int HWs[3] = {64*64, 32*32, 16*16};

  // workspace carve-up (floats)
  float* ws = (float*)d_ws;
  size_t off = 0;
  float* gray  = ws + off; off += (size_t)B*512*512;
  float* flags = ws + off; off += (size_t)B*127*127 + 8;
  float* ri[3]; float* di[3];
  for (int s=0;s<3;++s){
    ri[s] = ws + off; off += (size_t)B*hs[s]*hs[s];
    di[s] = ws + off; off += (size_t)B*hs[s]*hs[s];
  }
  float* convb  = ws + off; off += (size_t)B*256*64*64;   // max conv output
  float* alpha  = ws + off; off += 1024;
  float* beta   = ws + off; off += 1024;
  float* spmean = ws + off; off += (size_t)B*64*64;
  float* spmax  = ws + off; off += (size_t)B*64*64;
  float* swb    = ws + off; off += (size_t)B*64*64;
  float* gap    = ws + off; off += (size_t)B*1024;
  float* cwb    = ws + off; off += (size_t)B*1024;

  // stage A: masks
  k_gray <<<(B*512*512+255)/256, 256, 0, stream>>>(rgb_img, gray, B);
  k_flags<<<(B*127*127+255)/256, 256, 0, stream>>>(gray, flags, B);
  for (int s=0;s<3;++s)
    k_masks<<<(B*hs[s]*hs[s]+255)/256, 256, 0, stream>>>(flags, dep_img, ri[s], di[s], B, hs[s], sts[s]);

  const size_t outoff_r[3] = {0,            8388608u,  12582912u};
  const size_t outoff_d[3] = {14680064u,    23068672u, 27262976u};
  float* outp = (float*)d_out;

  for (int s=0;s<3;++s){
    const float* ftw = (const float*)d_in[8 +6*s];
    const float* bng = (const float*)d_in[9 +6*s];
    const float* bnb = (const float*)d_in[10+6*s];
    const float* saw = (const float*)d_in[11+6*s];
    const float* ca1 = (const float*)d_in[12+6*s];
    const float* ca2 = (const float*)d_in[13+6*s];
    int C = Cs[s], HW = HWs[s], h = hs[s];
    int R = C/16;

    for (int dir=0; dir<2; ++dir){
      const float* mainp = (dir==0) ? rgb_feat[s] : dep_feat[s];
      const float* auxp  = (dir==0) ? dep_feat[s] : rgb_feat[s];
      const float* maskp = (dir==0) ? ri[s] : di[s];
      float* outbase = outp + ((dir==0) ? outoff_r[s] : outoff_d[s]);

      if (s==0) k_conv3x3<16,64><<<dim3(B*4, 256),  256, 0, stream>>>(auxp, ftw, convb, B, C, h, h);
      if (s==1) k_conv3x3<32,32><<<dim3(B,   512),  256, 0, stream>>>(auxp, ftw, convb, B, C, h, h);
      if (s==2) k_conv3x3<16,16><<<dim3(B,  1024),   64, 0, stream>>>(auxp, ftw, convb, B, C, h, h);

      k_bnstats<<<C, 256, 0, stream>>>(convb, bng, bnb, alpha, beta, B, C, HW);

      if (s==0) k_spstats<4> <<<512, 256, 0, stream>>>(mainp, spmean, spmax, B, C, HW);
      if (s==1) k_spstats<8> <<<256, 256, 0, stream>>>(mainp, spmean, spmax, B, C, HW);
      if (s==2) k_spstats<32><<<256, 256, 0, stream>>>(mainp, spmean, spmax, B, C, HW);

      k_sw <<<(B*HW+255)/256, 256, 0, stream>>>(spmean, spmax, saw, swb, B, h, h);
      k_gap<<<B*C, 64, 0, stream>>>(mainp, gap, C, HW);
      k_mlp<<<B, 256, 0, stream>>>(gap, ca1, ca2, cwb, C, R);

      size_t N = (size_t)B*C*HW;
      k_final<<<(unsigned)((N+255)/256), 256, 0, stream>>>(mainp, convb, alpha, beta, swb, cwb, maskp, outbase, B, C, HW);
    }
  }
}

// Round 2
// 1490.090 us; speedup vs baseline: 13.9712x; 13.9712x over previous
//
#include <hip/hip_runtime.h>
#include <math.h>

#define B8 8
typedef unsigned short ushort_t;
typedef __attribute__((ext_vector_type(8))) short bf16x8;
typedef __attribute__((ext_vector_type(4))) float f32x4;

static __device__ __forceinline__ float sigmoidf_(float x){ return 1.f/(1.f+expf(-x)); }

static __device__ __forceinline__ ushort_t f2bf(float f){
  unsigned u = __float_as_uint(f);
  u = u + 0x7fffu + ((u>>16)&1u);
  return (ushort_t)(u>>16);
}

__device__ __forceinline__ void gload_lds16(const ushort_t* g, ushort_t* l){
  __builtin_amdgcn_global_load_lds((const __attribute__((address_space(1))) unsigned int*)(const void*)g,
                                   (__attribute__((address_space(3))) unsigned int*)(void*)l, 16, 0, 0);
}

// ---------------- gray ----------------
__global__ void k_gray(const float* __restrict__ rgb, float* __restrict__ gray, int B){
  const int HW = 512*512;
  int idx = blockIdx.x*256 + threadIdx.x;
  if (idx >= B*HW) return;
  int b = idx / HW, i = idx % HW;
  const float* p = rgb + (size_t)b*3*HW;
  float v = 0.299f*p[i] + 0.587f*p[i+HW] + 0.114f*p[i+2*HW];
  v *= 255.f;
  v = fminf(fmaxf(v, 0.f), 255.f);
  gray[idx] = v;
}

// ---------------- blur flags ----------------
__global__ void k_flags(const float* __restrict__ gray, float* __restrict__ flags, int B){
  const int NW = 127*127;
  int idx = blockIdx.x*256 + threadIdx.x;
  if (idx >= B*NW) return;
  int b = idx/NW, r = idx%NW;
  int wy = r/127, wx = r%127;
  const float* g = gray + (size_t)b*512*512;
  float s1 = 0.f, s2 = 0.f;
  for (int iy=0; iy<8; ++iy){
    int y = 4*wy + iy;
    for (int ix=0; ix<8; ++ix){
      int x = 4*wx + ix;
      float c  = g[y*512+x];
      float up = (y>0)   ? g[(y-1)*512+x] : 0.f;
      float dn = (y<511) ? g[(y+1)*512+x] : 0.f;
      float lf = (x>0)   ? g[y*512+x-1]   : 0.f;
      float rt = (x<511) ? g[y*512+x+1]   : 0.f;
      float lap = up+dn+lf+rt - 4.f*c;
      s1 += lap; s2 += lap*lap;
    }
  }
  float var = (s2 - s1*s1*(1.f/64.f)) * (1.f/63.f);
  flags[idx] = (var < 50.f) ? 1.f : 0.f;
}

// ---------------- downsampled masks ----------------
__global__ void k_masks(const float* __restrict__ flags, const float* __restrict__ depth,
                        float* __restrict__ ri, float* __restrict__ di,
                        int B, int h, int st){
  int n = B*h*h;
  int idx = blockIdx.x*256 + threadIdx.x;
  if (idx >= n) return;
  int b = idx/(h*h), i = idx%(h*h);
  int y = (i/h)*st, x = (i%h)*st;
  const float* f = flags + (size_t)b*127*127;
  int fy = y>>2, fx = x>>2;
  float v = f[fy*127+fx];
  if (y>0)         v = fmaxf(v, f[(fy-1)*127+fx]);
  if (x>0)         v = fmaxf(v, f[fy*127+fx-1]);
  if (y>0 && x>0)  v = fmaxf(v, f[(fy-1)*127+fx-1]);
  ri[idx] = v;
  const int IHW = 512*512;
  di[idx] = (depth[(size_t)b*3*IHW + 2*IHW + (size_t)y*512 + x] <= 0.f) ? 1.f : 0.f;
}

// ---------------- weights -> bf16, reordered [co][(ky*3+kx)*C + ci] ----------------
__global__ void k_wrd(const float* __restrict__ w, ushort_t* __restrict__ outp, int C){
  size_t total = (size_t)C*9*C;
  size_t idx = (size_t)blockIdx.x*256 + threadIdx.x;
  if (idx >= total) return;
  int ci = (int)(idx % C);
  size_t t = idx / C;
  int kq = (int)(t % 9);
  int co = (int)(t / 9);
  outp[idx] = f2bf(w[((size_t)co*C + ci)*9 + kq]);
}

// ---------------- input -> padded NHWC bf16: [b][y+1][x+1][c] ----------------
__global__ void k_nhwc(const float* __restrict__ in, ushort_t* __restrict__ outp,
                       int C, int H, int W){
  int H2 = H+2, W2 = W+2;
  size_t total = (size_t)B8*H2*W2*C;
  size_t idx = (size_t)blockIdx.x*256 + threadIdx.x;
  if (idx >= total) return;
  int c = (int)(idx % C);
  size_t t = idx / C;
  int xx = (int)(t % W2); t /= W2;
  int yy = (int)(t % H2);
  int b  = (int)(t / H2);
  float v = 0.f;
  if (yy>=1 && yy<=H && xx>=1 && xx<=W)
    v = in[((size_t)(b*C + c)*H + (yy-1))*W + (xx-1)];
  outp[idx] = f2bf(v);
}

// ---------------- implicit-GEMM conv: out[C][B*HW] = Aw[C][9C] * B(nhwc) ----------------
__global__ __launch_bounds__(256)
void k_gemm_conv(const ushort_t* __restrict__ Aw, const ushort_t* __restrict__ nh,
                 float* __restrict__ outp, int C, int H, int W){
  const int K9 = 9*C;
  const int HW = H*W;
  const int N  = B8*HW;
  const int H2 = H+2, W2 = W+2;
  __shared__ ushort_t sA[128*64];
  __shared__ ushort_t sB[128*64];
  int t = threadIdx.x;
  int m0 = blockIdx.y*128, n0 = blockIdx.x*128;
  int l = t & 63, wv = t >> 6;
  int wm = wv >> 1, wn = wv & 1;

  int trow = t >> 3;             // 0..31
  int k8   = (t & 7) * 8;        // 0,8,..,56
  long long aoff[4], boff[4];
  #pragma unroll
  for (int i=0;i<4;++i){
    int row = trow + 32*i;
    aoff[i] = (long long)(m0 + row)*K9 + k8;
    int n = n0 + row;
    int b = n / HW, r = n % HW;
    int y = r / W,  x = r % W;
    boff[i] = ((long long)(b*H2 + y + 1)*W2 + (x + 1))*(long long)C + k8;
  }
  f32x4 acc[4][4];
  #pragma unroll
  for (int i=0;i<4;++i)
    #pragma unroll
    for (int j=0;j<4;++j) acc[i][j] = (f32x4){0.f,0.f,0.f,0.f};

  int lrow = l & 15, lk = (l >> 4)*8;

  for (int kq=0; kq<9; ++kq){
    long long duvC = (long long)((kq/3 - 1)*W2 + (kq%3 - 1)) * C;
    long long acol = (long long)kq*C;
    for (int c0=0; c0<C; c0+=64){
      #pragma unroll
      for (int i=0;i<4;++i){
        gload_lds16(Aw + aoff[i] + acol + c0, &sA[0] + 8*t + 2048*i);
        gload_lds16(nh + boff[i] + duvC + c0, &sB[0] + 8*t + 2048*i);
      }
      __syncthreads();
      bf16x8 af[4][2], bfr[4][2];
      #pragma unroll
      for (int mi=0;mi<4;++mi)
        #pragma unroll
        for (int kk=0;kk<2;++kk){
          af[mi][kk]  = *(const bf16x8*)&sA[(wm*64 + mi*16 + lrow)*64 + kk*32 + lk];
          bfr[mi][kk] = *(const bf16x8*)&sB[(wn*64 + mi*16 + lrow)*64 + kk*32 + lk];
        }
      #pragma unroll
      for (int kk=0;kk<2;++kk)
        #pragma unroll
        for (int mi=0;mi<4;++mi)
          #pragma unroll
          for (int ni=0;ni<4;++ni)
            acc[mi][ni] = __builtin_amdgcn_mfma_f32_16x16x32_bf16(af[mi][kk], bfr[ni][kk], acc[mi][ni], 0,0,0);
      __syncthreads();
    }
  }
  int orow = m0 + wm*64 + (l>>4)*4;
  int ocol = n0 + wn*64 + (l&15);
  #pragma unroll
  for (int mi=0;mi<4;++mi)
    #pragma unroll
    for (int ni=0;ni<4;++ni)
      #pragma unroll
      for (int r=0;r<4;++r)
        outp[(size_t)(orow + mi*16 + r)*N + ocol + ni*16] = acc[mi][ni][r];
}

// ---------------- BN stats from conv layout [C][B*HW] ----------------
__global__ void k_bnstats(const float* __restrict__ conv, const float* __restrict__ g,
                          const float* __restrict__ bb, float* __restrict__ alpha,
                          float* __restrict__ beta, int C, int BHW){
  int c = blockIdx.x;
  int tid = threadIdx.x;
  const float* p = conv + (size_t)c*BHW;
  float s1=0.f, s2=0.f;
  for (int i=tid;i<BHW;i+=256){ float v=p[i]; s1+=v; s2+=v*v; }
  __shared__ float sb1[4], sb2[4];
  #pragma unroll
  for (int off=32; off; off>>=1){ s1 += __shfl_down(s1,off); s2 += __shfl_down(s2,off); }
  int wid = tid>>6;
  if ((tid&63)==0){ sb1[wid]=s1; sb2[wid]=s2; }
  __syncthreads();
  if (tid==0){
    s1 = sb1[0]+sb1[1]+sb1[2]+sb1[3];
    s2 = sb2[0]+sb2[1]+sb2[2]+sb2[3];
    float Nf = (float)BHW;
    float mean = s1/Nf;
    float var  = s2/Nf - mean*mean;
    float a = g[c] / sqrtf(var + 1e-5f);
    alpha[c] = a;
    beta[c]  = bb[c] - mean*a;
  }
}

// ---------------- per-position channel mean/max ----------------
template<int NS>
__global__ void k_spstats(const float* __restrict__ main_, float* __restrict__ spmean,
                          float* __restrict__ spmax, int B, int C, int HW){
  int tid = threadIdx.x;
  int slice = tid % NS;
  int pos = blockIdx.x*(256/NS) + tid/NS;
  int b = pos / HW, i = pos % HW;
  const float* p = main_ + (size_t)b*C*HW + i;
  float sum = 0.f, mx = -INFINITY;
  for (int c=slice; c<C; c+=NS){
    float v = p[(size_t)c*HW];
    sum += v; mx = fmaxf(mx, v);
  }
  #pragma unroll
  for (int off=NS/2; off; off>>=1){
    sum += __shfl_xor(sum, off);
    mx = fmaxf(mx, __shfl_xor(mx, off));
  }
  if (slice==0){ spmean[pos] = sum/C; spmax[pos] = mx; }
}

// ---------------- spatial attention ----------------
__global__ void k_sw(const float* __restrict__ spmean, const float* __restrict__ spmax,
                     const float* __restrict__ sa, float* __restrict__ sw,
                     int B, int H, int W){
  __shared__ float s_sa[196];
  int tid = threadIdx.x;
  if (tid < 196) s_sa[tid] = sa[tid];
  __syncthreads();
  int HW = H*W;
  int gpos = blockIdx.x*256 + tid;
  if (gpos >= B*HW) return;
  int b = gpos/HW, i = gpos%HW;
  int y = i/W, x = i%W;
  float inv_w = 2.f/(float)(W-1), inv_h = 2.f/(float)(H-1);
  const float* pm = spmean + (size_t)b*HW;
  const float* px = spmax  + (size_t)b*HW;
  float acc = 0.f;
  for (int ky=0;ky<7;++ky){
    int yy = y+ky-3;
    if (yy<0 || yy>=H) continue;
    float ysv = -1.f + yy*inv_h;
    for (int kx=0;kx<7;++kx){
      int xx = x+kx-3;
      if (xx<0 || xx>=W) continue;
      float xsv = -1.f + xx*inv_w;
      int kk = ky*7+kx;
      acc += s_sa[kk]*pm[yy*W+xx] + s_sa[49+kk]*px[yy*W+xx]
           + s_sa[98+kk]*xsv + s_sa[147+kk]*ysv;
    }
  }
  sw[gpos] = sigmoidf_(acc);
}

// ---------------- global average pool ----------------
__global__ void k_gap(const float* __restrict__ main_, float* __restrict__ gap,
                      int C, int HW){
  const float* p = main_ + (size_t)blockIdx.x*HW;
  float s = 0.f;
  for (int i=threadIdx.x; i<HW; i+=64) s += p[i];
  #pragma unroll
  for (int off=32; off; off>>=1) s += __shfl_down(s, off);
  if (threadIdx.x==0) gap[blockIdx.x] = s/(float)HW;
}

// ---------------- channel attention MLP ----------------
__global__ void k_mlp(const float* __restrict__ gap, const float* __restrict__ w1,
                      const float* __restrict__ w2, float* __restrict__ cw,
                      int C, int R){
  int b = blockIdx.x;
  int tid = threadIdx.x;
  __shared__ float sg[1024];
  __shared__ float sh[64];
  const float* gp = gap + (size_t)b*C;
  for (int c=tid;c<C;c+=256) sg[c]=gp[c];
  __syncthreads();
  int r = tid>>2, q = tid&3;
  if (r < R){
    float s = 0.f;
    for (int c=q;c<C;c+=4) s += w1[(size_t)r*C + c]*sg[c];
    s += __shfl_xor(s,1); s += __shfl_xor(s,2);
    if (q==0) sh[r] = fmaxf(s, 0.f);
  }
  __syncthreads();
  for (int c2=tid; c2<C; c2+=256){
    float s = 0.f;
    for (int rr=0;rr<R;++rr) s += w2[(size_t)c2*R + rr]*sh[rr];
    cw[(size_t)b*C + c2] = sigmoidf_(s);
  }
}

// ---------------- final masked compose (conv in [C][B*HW]) ----------------
__global__ void k_final(const float* __restrict__ main_, const float* __restrict__ conv,
                        const float* __restrict__ alpha, const float* __restrict__ beta,
                        const float* __restrict__ sw, const float* __restrict__ cw,
                        const float* __restrict__ mask, float* __restrict__ out,
                        int C, int HW){
  size_t idx = (size_t)blockIdx.x*256 + threadIdx.x;
  size_t N = (size_t)B8*C*HW;
  if (idx >= N) return;
  int i = (int)(idx % HW);
  size_t t = idx / HW;
  int c = (int)(t % C);
  int b = (int)(t / C);
  float m = mask[(size_t)b*HW + i];
  float res;
  if (m > 0.5f){
    float cv = conv[(size_t)c*(B8*HW) + (size_t)b*HW + i];
    float at = fmaxf(alpha[c]*cv + beta[c], 0.f);
    res = 2.f*at*sw[(size_t)b*HW + i]*cw[(size_t)b*C + c];
  } else {
    res = main_[idx];
  }
  out[idx] = res;
}

extern "C" void kernel_launch(void* const* d_in, const int* in_sizes, int n_in,
                              void* d_out, int out_size, void* d_ws, size_t ws_size,
                              hipStream_t stream){
  (void)in_sizes; (void)n_in; (void)out_size; (void)ws_size;
  const int B = B8;
  const float* rgb_feat[3] = {(const float*)d_in[0], (const float*)d_in[2], (const float*)d_in[4]};
  const float* dep_feat[3] = {(const float*)d_in[1], (const float*)d_in[3], (const float*)d_in[5]};
  const float* rgb_img = (const float*)d_in[6];
  const float* dep_img = (const float*)d_in[7];

  const int Cs[3]  = {256, 512, 1024};
  const int hs[3]  = {64, 32, 16};
  const int sts[3] = {8, 16, 32};
  const int HWs[3] = {64*64, 32*32, 16*16};

  float* ws = (float*)d_ws;
  size_t off = 0;
  auto alloc = [&](size_t n){ float* p = ws + off; off += (n + 15) & ~(size_t)15; return p; };

  float* ri[3]; float* di[3];
  for (int s=0;s<3;++s){
    ri[s] = alloc((size_t)B*hs[s]*hs[s]);
    di[s] = alloc((size_t)B*hs[s]*hs[s]);
  }
  ushort_t* wbf  = (ushort_t*)alloc(4718592);   // max 1024*9216 bf16
  ushort_t* nhbf = (ushort_t*)alloc(4460544);   // max 8*66*66*256 bf16
  float* convb   = alloc(8388608);              // [C][B*HW] fp32, max scale 0
  float* alphab  = alloc(1024);
  float* betab   = alloc(1024);
  float* spmean  = alloc(32768);
  float* spmax   = alloc(32768);
  float* swb     = alloc(32768);
  float* gapb    = alloc(8192);
  float* cwb     = alloc(8192);
  // gray/flags alias convb region (dead before any conv output is produced)
  float* gray  = convb;
  float* flags = convb + 2097152;

  // stage A: masks
  k_gray <<<(B*512*512+255)/256, 256, 0, stream>>>(rgb_img, gray, B);
  k_flags<<<(B*127*127+255)/256, 256, 0, stream>>>(gray, flags, B);
  for (int s=0;s<3;++s)
    k_masks<<<(B*hs[s]*hs[s]+255)/256, 256, 0, stream>>>(flags, dep_img, ri[s], di[s], B, hs[s], sts[s]);

  const size_t outoff_r[3] = {0,         8388608u,  12582912u};
  const size_t outoff_d[3] = {14680064u, 23068672u, 27262976u};
  float* outp = (float*)d_out;

  for (int s=0;s<3;++s){
    const float* ftw = (const float*)d_in[8 +6*s];
    const float* bng = (const float*)d_in[9 +6*s];
    const float* bnb = (const float*)d_in[10+6*s];
    const float* saw = (const float*)d_in[11+6*s];
    const float* ca1 = (const float*)d_in[12+6*s];
    const float* ca2 = (const float*)d_in[13+6*s];
    int C = Cs[s], HW = HWs[s], h = hs[s];
    int R = C/16;
    int BHW = B*HW;

    // weights bf16 reorder (shared by both directions)
    {
      size_t tot = (size_t)C*9*C;
      k_wrd<<<(unsigned)((tot+255)/256), 256, 0, stream>>>(ftw, wbf, C);
    }

    for (int dir=0; dir<2; ++dir){
      const float* mainp = (dir==0) ? rgb_feat[s] : dep_feat[s];
      const float* auxp  = (dir==0) ? dep_feat[s] : rgb_feat[s];
      const float* maskp = (dir==0) ? ri[s] : di[s];
      float* outbase = outp + ((dir==0) ? outoff_r[s] : outoff_d[s]);

      // aux -> padded NHWC bf16
      {
        size_t tot = (size_t)B*(h+2)*(h+2)*C;
        k_nhwc<<<(unsigned)((tot+255)/256), 256, 0, stream>>>(auxp, nhbf, C, h, h);
      }
      // implicit GEMM conv
      k_gemm_conv<<<dim3(BHW/128, C/128), 256, 0, stream>>>(wbf, nhbf, convb, C, h, h);

      k_bnstats<<<C, 256, 0, stream>>>(convb, bng, bnb, alphab, betab, C, BHW);

      if (s==0) k_spstats<4> <<<512, 256, 0, stream>>>(mainp, spmean, spmax, B, C, HW);
      if (s==1) k_spstats<8> <<<256, 256, 0, stream>>>(mainp, spmean, spmax, B, C, HW);
      if (s==2) k_spstats<32><<<256, 256, 0, stream>>>(mainp, spmean, spmax, B, C, HW);

      k_sw <<<(B*HW+255)/256, 256, 0, stream>>>(spmean, spmax, saw, swb, B, h, h);
      k_gap<<<B*C, 64, 0, stream>>>(mainp, gapb, C, HW);
      k_mlp<<<B, 256, 0, stream>>>(gapb, ca1, ca2, cwb, C, R);

      size_t N = (size_t)B*C*HW;
      k_final<<<(unsigned)((N+255)/256), 256, 0, stream>>>(mainp, convb, alphab, betab, swb, cwb, maskp, outbase, C, HW);
    }
  }
}

// Round 3
// 1170.690 us; speedup vs baseline: 17.7829x; 1.2728x over previous
//
#include <hip/hip_runtime.h>
#include <math.h>

#define B8 8
typedef unsigned short ushort_t;
typedef __attribute__((ext_vector_type(8))) short bf16x8;
typedef __attribute__((ext_vector_type(4))) float f32x4;

static __device__ __forceinline__ float sigmoidf_(float x){ return 1.f/(1.f+expf(-x)); }

static __device__ __forceinline__ ushort_t f2bf(float f){
  unsigned u = __float_as_uint(f);
  u = u + 0x7fffu + ((u>>16)&1u);
  return (ushort_t)(u>>16);
}

__device__ __forceinline__ void gload_lds16(const ushort_t* g, ushort_t* l){
  __builtin_amdgcn_global_load_lds((const __attribute__((address_space(1))) unsigned int*)(const void*)g,
                                   (__attribute__((address_space(3))) unsigned int*)(void*)l, 16, 0, 0);
}

// ---------------- fused gray+laplacian+window-variance flags ----------------
// block = 256 threads = 16x16 windows; LDS tile of gray 70x70 (halo'd)
__global__ __launch_bounds__(256) void k_flags2(const float* __restrict__ rgb,
                                                float* __restrict__ flags){
  __shared__ float sg[70][71];
  int bx = blockIdx.x & 7, by = (blockIdx.x >> 3) & 7, b = blockIdx.x >> 6;
  int wy0 = by*16, wx0 = bx*16;
  int y0 = 4*wy0 - 1, x0 = 4*wx0 - 1;
  const float* p = rgb + (size_t)b*3*262144;
  int tid = threadIdx.x;
  for (int i = tid; i < 70*70; i += 256){
    int r = i/70, cX = i%70;
    int y = y0 + r, x = x0 + cX;
    float v = 0.f;
    if (y>=0 && y<512 && x>=0 && x<512){
      int ii = y*512+x;
      v = 0.299f*p[ii] + 0.587f*p[ii+262144] + 0.114f*p[ii+524288];
      v = fminf(fmaxf(v*255.f, 0.f), 255.f);
    }
    sg[r][cX] = v;
  }
  __syncthreads();
  int wy = wy0 + (tid>>4), wx = wx0 + (tid&15);
  if (wy > 126 || wx > 126) return;
  int ry = 4*(tid>>4) + 1, rx = 4*(tid&15) + 1;
  float s1 = 0.f, s2 = 0.f;
  #pragma unroll
  for (int iy=0; iy<8; ++iy){
    int r = ry+iy;
    #pragma unroll
    for (int ix=0; ix<8; ++ix){
      int cX = rx+ix;
      float c = sg[r][cX];
      float lap = sg[r-1][cX] + sg[r+1][cX] + sg[r][cX-1] + sg[r][cX+1] - 4.f*c;
      s1 += lap; s2 += lap*lap;
    }
  }
  float var = (s2 - s1*s1*(1.f/64.f)) * (1.f/63.f);
  flags[(size_t)b*16129 + wy*127 + wx] = (var < 50.f) ? 1.f : 0.f;
}

// ---------------- downsampled masks ----------------
__global__ void k_masks(const float* __restrict__ flags, const float* __restrict__ depth,
                        float* __restrict__ ri, float* __restrict__ di,
                        int B, int h, int st){
  int n = B*h*h;
  int idx = blockIdx.x*256 + threadIdx.x;
  if (idx >= n) return;
  int b = idx/(h*h), i = idx%(h*h);
  int y = (i/h)*st, x = (i%h)*st;
  const float* f = flags + (size_t)b*16129;
  int fy = y>>2, fx = x>>2;
  float v = f[fy*127+fx];
  if (y>0)         v = fmaxf(v, f[(fy-1)*127+fx]);
  if (x>0)         v = fmaxf(v, f[fy*127+fx-1]);
  if (y>0 && x>0)  v = fmaxf(v, f[(fy-1)*127+fx-1]);
  ri[idx] = v;
  const int IHW = 262144;
  di[idx] = (depth[(size_t)b*3*IHW + 2*IHW + (size_t)y*512 + x] <= 0.f) ? 1.f : 0.f;
}

// ---------------- weights -> bf16, reordered [co][(ky*3+kx)*C + ci] ----------------
__global__ void k_wrd(const float* __restrict__ w, ushort_t* __restrict__ outp, int C){
  size_t total = (size_t)C*9*C;
  size_t idx = (size_t)blockIdx.x*256 + threadIdx.x;
  if (idx >= total) return;
  int ci = (int)(idx % C);
  size_t t = idx / C;
  int kq = (int)(t % 9);
  int co = (int)(t / 9);
  outp[idx] = f2bf(w[((size_t)co*C + ci)*9 + kq]);
}

// ---------------- input -> padded NHWC bf16: [b][y+1][x+1][c] ----------------
__global__ void k_nhwc(const float* __restrict__ in, ushort_t* __restrict__ outp,
                       int C, int H, int W){
  int H2 = H+2, W2 = W+2;
  size_t total = (size_t)B8*H2*W2*C;
  size_t idx = (size_t)blockIdx.x*256 + threadIdx.x;
  if (idx >= total) return;
  int c = (int)(idx % C);
  size_t t = idx / C;
  int xx = (int)(t % W2); t /= W2;
  int yy = (int)(t % H2);
  int b  = (int)(t / H2);
  float v = 0.f;
  if (yy>=1 && yy<=H && xx>=1 && xx<=W)
    v = in[((size_t)(b*C + c)*H + (yy-1))*W + (xx-1)];
  outp[idx] = f2bf(v);
}

// ---------------- implicit-GEMM conv with split-K ----------------
// out partial[kz][C][B*HW]; K' = kq*C+ci; 128x128 tile, BK=64, 4 waves
template<int C, int H, int W, int KS>
__global__ __launch_bounds__(256)
void k_gemm_conv(const ushort_t* __restrict__ Aw, const ushort_t* __restrict__ nh,
                 float* __restrict__ outp){
  const int K9 = 9*C;
  const int HW = H*W;
  const int N  = B8*HW;
  const int H2 = H+2, W2 = W+2;
  const int NT_N = N/128, NT_M = C/128;
  const int KCT = (K9/64)/KS;               // K-steps per WG (=36 for all scales)
  __shared__ ushort_t sA[128*64];
  __shared__ ushort_t sB[128*64];
  int t = threadIdx.x;

  // bijective XCD swizzle over linearized grid (nwg = NT_N*NT_M*KS = 512)
  const int nwg = NT_N*NT_M*KS;
  int bid = blockIdx.x;
  int swz = (bid & 7)*(nwg >> 3) + (bid >> 3);
  int n_t = swz % NT_N; int tmp = swz / NT_N;
  int m_t = tmp % NT_M; int kz  = tmp / NT_M;

  int m0 = m_t*128, n0 = n_t*128;
  int l = t & 63, wv = t >> 6;
  int wm = wv >> 1, wn = wv & 1;

  int trow = t >> 3;             // 0..31
  int k8   = (t & 7) * 8;        // 0,8,..,56
  long long aoff[4], boff[4];
  #pragma unroll
  for (int i=0;i<4;++i){
    int row = trow + 32*i;
    aoff[i] = (long long)(m0 + row)*K9 + k8;
    int n = n0 + row;
    int b = n / HW, r = n % HW;
    int y = r / W,  x = r % W;
    boff[i] = ((long long)(b*H2 + y + 1)*W2 + (x + 1))*(long long)C + k8;
  }
  f32x4 acc[4][4];
  #pragma unroll
  for (int i=0;i<4;++i)
    #pragma unroll
    for (int j=0;j<4;++j) acc[i][j] = (f32x4){0.f,0.f,0.f,0.f};

  int lrow = l & 15, lk = (l >> 4)*8;

  int kc0 = kz*KCT, kc1 = kc0 + KCT;
  for (int kc = kc0; kc < kc1; ++kc){
    int off = kc << 6;
    int kq  = off / C;                      // C is power of 2 -> shift
    int c0  = off & (C-1);
    int dy = kq/3 - 1, dx = kq%3 - 1;
    long long duvC = (long long)(dy*W2 + dx)*C;
    #pragma unroll
    for (int i=0;i<4;++i){
      gload_lds16(Aw + aoff[i] + off,              &sA[0] + 8*t + 2048*i);
      gload_lds16(nh + boff[i] + duvC + c0,        &sB[0] + 8*t + 2048*i);
    }
    __syncthreads();
    bf16x8 af[4][2], bfr[4][2];
    #pragma unroll
    for (int mi=0;mi<4;++mi)
      #pragma unroll
      for (int kk=0;kk<2;++kk){
        af[mi][kk]  = *(const bf16x8*)&sA[(wm*64 + mi*16 + lrow)*64 + kk*32 + lk];
        bfr[mi][kk] = *(const bf16x8*)&sB[(wn*64 + mi*16 + lrow)*64 + kk*32 + lk];
      }
    #pragma unroll
    for (int kk=0;kk<2;++kk)
      #pragma unroll
      for (int mi=0;mi<4;++mi)
        #pragma unroll
        for (int ni=0;ni<4;++ni)
          acc[mi][ni] = __builtin_amdgcn_mfma_f32_16x16x32_bf16(af[mi][kk], bfr[ni][kk], acc[mi][ni], 0,0,0);
    __syncthreads();
  }
  float* po = outp + (size_t)kz*C*N;
  int orow = m0 + wm*64 + (l>>4)*4;
  int ocol = n0 + wn*64 + (l&15);
  #pragma unroll
  for (int mi=0;mi<4;++mi)
    #pragma unroll
    for (int ni=0;ni<4;++ni)
      #pragma unroll
      for (int r=0;r<4;++r)
        po[(size_t)(orow + mi*16 + r)*N + ocol + ni*16] = acc[mi][ni][r];
}

// ---------------- split-K reduce + BN stats fused (one block per channel row) ----------------
__global__ __launch_bounds__(256)
void k_redbn(const float* __restrict__ pbuf, float* __restrict__ convb,
             const float* __restrict__ g, const float* __restrict__ bb,
             float* __restrict__ alpha, float* __restrict__ beta,
             int N, int ks, int C){
  int c = blockIdx.x, tid = threadIdx.x;
  size_t MN = (size_t)C*N;
  const float* p0 = pbuf + (size_t)c*N;
  float* po = convb + (size_t)c*N;
  float s1 = 0.f, s2 = 0.f;
  for (int i = tid*4; i < N; i += 1024){
    float4 v = *(const float4*)(p0 + i);
    for (int kz=1; kz<ks; ++kz){
      const float4 w = *(const float4*)(p0 + (size_t)kz*MN + i);
      v.x += w.x; v.y += w.y; v.z += w.z; v.w += w.w;
    }
    *(float4*)(po + i) = v;
    s1 += v.x + v.y + v.z + v.w;
    s2 += v.x*v.x + v.y*v.y + v.z*v.z + v.w*v.w;
  }
  __shared__ float sb1[4], sb2[4];
  #pragma unroll
  for (int off=32; off; off>>=1){ s1 += __shfl_down(s1,off); s2 += __shfl_down(s2,off); }
  int wid = tid>>6;
  if ((tid&63)==0){ sb1[wid]=s1; sb2[wid]=s2; }
  __syncthreads();
  if (tid==0){
    s1 = sb1[0]+sb1[1]+sb1[2]+sb1[3];
    s2 = sb2[0]+sb2[1]+sb2[2]+sb2[3];
    float Nf = (float)N;
    float mean = s1/Nf;
    float var  = s2/Nf - mean*mean;
    float a = g[c] / sqrtf(var + 1e-5f);
    alpha[c] = a;
    beta[c]  = bb[c] - mean*a;
  }
}

// ---------------- per-position channel mean/max ----------------
template<int NS>
__global__ void k_spstats(const float* __restrict__ main_, float* __restrict__ spmean,
                          float* __restrict__ spmax, int B, int C, int HW){
  int tid = threadIdx.x;
  int slice = tid % NS;
  int pos = blockIdx.x*(256/NS) + tid/NS;
  int b = pos / HW, i = pos % HW;
  const float* p = main_ + (size_t)b*C*HW + i;
  float sum = 0.f, mx = -INFINITY;
  for (int c=slice; c<C; c+=NS){
    float v = p[(size_t)c*HW];
    sum += v; mx = fmaxf(mx, v);
  }
  #pragma unroll
  for (int off=NS/2; off; off>>=1){
    sum += __shfl_xor(sum, off);
    mx = fmaxf(mx, __shfl_xor(mx, off));
  }
  if (slice==0){ spmean[pos] = sum/C; spmax[pos] = mx; }
}

// ---------------- spatial attention ----------------
__global__ void k_sw(const float* __restrict__ spmean, const float* __restrict__ spmax,
                     const float* __restrict__ sa, float* __restrict__ sw,
                     int B, int H, int W){
  __shared__ float s_sa[196];
  int tid = threadIdx.x;
  if (tid < 196) s_sa[tid] = sa[tid];
  __syncthreads();
  int HW = H*W;
  int gpos = blockIdx.x*256 + tid;
  if (gpos >= B*HW) return;
  int b = gpos/HW, i = gpos%HW;
  int y = i/W, x = i%W;
  float inv_w = 2.f/(float)(W-1), inv_h = 2.f/(float)(H-1);
  const float* pm = spmean + (size_t)b*HW;
  const float* px = spmax  + (size_t)b*HW;
  float acc = 0.f;
  for (int ky=0;ky<7;++ky){
    int yy = y+ky-3;
    if (yy<0 || yy>=H) continue;
    float ysv = -1.f + yy*inv_h;
    for (int kx=0;kx<7;++kx){
      int xx = x+kx-3;
      if (xx<0 || xx>=W) continue;
      float xsv = -1.f + xx*inv_w;
      int kk = ky*7+kx;
      acc += s_sa[kk]*pm[yy*W+xx] + s_sa[49+kk]*px[yy*W+xx]
           + s_sa[98+kk]*xsv + s_sa[147+kk]*ysv;
    }
  }
  sw[gpos] = sigmoidf_(acc);
}

// ---------------- global average pool ----------------
__global__ void k_gap(const float* __restrict__ main_, float* __restrict__ gap,
                      int C, int HW){
  const float* p = main_ + (size_t)blockIdx.x*HW;
  float s = 0.f;
  for (int i=threadIdx.x; i<HW; i+=64) s += p[i];
  #pragma unroll
  for (int off=32; off; off>>=1) s += __shfl_down(s, off);
  if (threadIdx.x==0) gap[blockIdx.x] = s/(float)HW;
}

// ---------------- channel attention MLP ----------------
__global__ void k_mlp(const float* __restrict__ gap, const float* __restrict__ w1,
                      const float* __restrict__ w2, float* __restrict__ cw,
                      int C, int R){
  int b = blockIdx.x;
  int tid = threadIdx.x;
  __shared__ float sg[1024];
  __shared__ float sh[64];
  const float* gp = gap + (size_t)b*C;
  for (int c=tid;c<C;c+=256) sg[c]=gp[c];
  __syncthreads();
  int r = tid>>2, q = tid&3;
  if (r < R){
    float s = 0.f;
    for (int c=q;c<C;c+=4) s += w1[(size_t)r*C + c]*sg[c];
    s += __shfl_xor(s,1); s += __shfl_xor(s,2);
    if (q==0) sh[r] = fmaxf(s, 0.f);
  }
  __syncthreads();
  for (int c2=tid; c2<C; c2+=256){
    float s = 0.f;
    for (int rr=0;rr<R;++rr) s += w2[(size_t)c2*R + rr]*sh[rr];
    cw[(size_t)b*C + c2] = sigmoidf_(s);
  }
}

// ---------------- final masked compose (conv in [C][B*HW]) ----------------
__global__ void k_final(const float* __restrict__ main_, const float* __restrict__ conv,
                        const float* __restrict__ alpha, const float* __restrict__ beta,
                        const float* __restrict__ sw, const float* __restrict__ cw,
                        const float* __restrict__ mask, float* __restrict__ out,
                        int C, int HW){
  size_t idx = (size_t)blockIdx.x*256 + threadIdx.x;
  size_t N = (size_t)B8*C*HW;
  if (idx >= N) return;
  int i = (int)(idx % HW);
  size_t t = idx / HW;
  int c = (int)(t % C);
  int b = (int)(t / C);
  float m = mask[(size_t)b*HW + i];
  float res;
  if (m > 0.5f){
    float cv = conv[(size_t)c*(B8*HW) + (size_t)b*HW + i];
    float at = fmaxf(alpha[c]*cv + beta[c], 0.f);
    res = 2.f*at*sw[(size_t)b*HW + i]*cw[(size_t)b*C + c];
  } else {
    res = main_[idx];
  }
  out[idx] = res;
}

extern "C" void kernel_launch(void* const* d_in, const int* in_sizes, int n_in,
                              void* d_out, int out_size, void* d_ws, size_t ws_size,
                              hipStream_t stream){
  (void)in_sizes; (void)n_in; (void)out_size; (void)ws_size;
  const int B = B8;
  const float* rgb_feat[3] = {(const float*)d_in[0], (const float*)d_in[2], (const float*)d_in[4]};
  const float* dep_feat[3] = {(const float*)d_in[1], (const float*)d_in[3], (const float*)d_in[5]};
  const float* rgb_img = (const float*)d_in[6];
  const float* dep_img = (const float*)d_in[7];

  const int Cs[3]  = {256, 512, 1024};
  const int hs[3]  = {64, 32, 16};
  const int sts[3] = {8, 16, 32};
  const int HWs[3] = {64*64, 32*32, 16*16};
  const int KSs[3] = {1, 2, 4};

  float* ws = (float*)d_ws;
  size_t off = 0;
  auto alloc = [&](size_t n){ float* p = ws + off; off += (n + 15) & ~(size_t)15; return p; };

  float* flags = alloc((size_t)B*16129);
  float* ri[3]; float* di[3];
  for (int s=0;s<3;++s){
    ri[s] = alloc((size_t)B*hs[s]*hs[s]);
    di[s] = alloc((size_t)B*hs[s]*hs[s]);
  }
  ushort_t* wbf  = (ushort_t*)alloc(4718592);   // max 1024*9216 bf16
  ushort_t* nhbf = (ushort_t*)alloc(4460544);   // max 8*66*66*256 bf16
  float* pbuf    = alloc(8388608);              // split-K partials (max ks*C*BHW)
  float* convb   = alloc(8388608);              // [C][B*HW] fp32
  float* alphab  = alloc(1024);
  float* betab   = alloc(1024);
  float* spmean  = alloc(32768);
  float* spmax   = alloc(32768);
  float* swb     = alloc(32768);
  float* gapb    = alloc(8192);
  float* cwb     = alloc(8192);

  // stage A: masks
  k_flags2<<<512, 256, 0, stream>>>(rgb_img, flags);
  for (int s=0;s<3;++s)
    k_masks<<<(B*hs[s]*hs[s]+255)/256, 256, 0, stream>>>(flags, dep_img, ri[s], di[s], B, hs[s], sts[s]);

  const size_t outoff_r[3] = {0,         8388608u,  12582912u};
  const size_t outoff_d[3] = {14680064u, 23068672u, 27262976u};
  float* outp = (float*)d_out;

  for (int s=0;s<3;++s){
    const float* ftw = (const float*)d_in[8 +6*s];
    const float* bng = (const float*)d_in[9 +6*s];
    const float* bnb = (const float*)d_in[10+6*s];
    const float* saw = (const float*)d_in[11+6*s];
    const float* ca1 = (const float*)d_in[12+6*s];
    const float* ca2 = (const float*)d_in[13+6*s];
    int C = Cs[s], HW = HWs[s], h = hs[s];
    int R = C/16;
    int BHW = B*HW;
    int ks = KSs[s];

    {
      size_t tot = (size_t)C*9*C;
      k_wrd<<<(unsigned)((tot+255)/256), 256, 0, stream>>>(ftw, wbf, C);
    }

    for (int dir=0; dir<2; ++dir){
      const float* mainp = (dir==0) ? rgb_feat[s] : dep_feat[s];
      const float* auxp  = (dir==0) ? dep_feat[s] : rgb_feat[s];
      const float* maskp = (dir==0) ? ri[s] : di[s];
      float* outbase = outp + ((dir==0) ? outoff_r[s] : outoff_d[s]);

      {
        size_t tot = (size_t)B*(h+2)*(h+2)*C;
        k_nhwc<<<(unsigned)((tot+255)/256), 256, 0, stream>>>(auxp, nhbf, C, h, h);
      }
      // implicit GEMM conv, split-K, 512 WGs each
      float* gout = (ks == 1) ? convb : pbuf;
      if (s==0) k_gemm_conv<256, 64,64,1><<<512, 256, 0, stream>>>(wbf, nhbf, gout);
      if (s==1) k_gemm_conv<512, 32,32,2><<<512, 256, 0, stream>>>(wbf, nhbf, gout);
      if (s==2) k_gemm_conv<1024,16,16,4><<<512, 256, 0, stream>>>(wbf, nhbf, gout);

      // reduce partials + BN stats fused (for ks==1 reads/writes convb in place)
      k_redbn<<<C, 256, 0, stream>>>(gout, convb, bng, bnb, alphab, betab, BHW, ks, C);

      if (s==0) k_spstats<4> <<<512, 256, 0, stream>>>(mainp, spmean, spmax, B, C, HW);
      if (s==1) k_spstats<8> <<<256, 256, 0, stream>>>(mainp, spmean, spmax, B, C, HW);
      if (s==2) k_spstats<32><<<256, 256, 0, stream>>>(mainp, spmean, spmax, B, C, HW);

      k_sw <<<(B*HW+255)/256, 256, 0, stream>>>(spmean, spmax, saw, swb, B, h, h);
      k_gap<<<B*C, 64, 0, stream>>>(mainp, gapb, C, HW);
      k_mlp<<<B, 256, 0, stream>>>(gapb, ca1, ca2, cwb, C, R);

      size_t N = (size_t)B*C*HW;
      k_final<<<(unsigned)((N+255)/256), 256, 0, stream>>>(mainp, convb, alphab, betab, swb, cwb, maskp, outbase, C, HW);
    }
  }
}

// Round 4
// 768.441 us; speedup vs baseline: 27.0916x; 1.5235x over previous
//
#include <hip/hip_runtime.h>
#include <math.h>

#define B8 8
typedef unsigned short ushort_t;
typedef __attribute__((ext_vector_type(8))) short bf16x8;
typedef __attribute__((ext_vector_type(4))) float f32x4;

static __device__ __forceinline__ float sigmoidf_(float x){ return 1.f/(1.f+expf(-x)); }

static __device__ __forceinline__ ushort_t f2bf(float f){
  unsigned u = __float_as_uint(f);
  u = u + 0x7fffu + ((u>>16)&1u);
  return (ushort_t)(u>>16);
}

__device__ __forceinline__ void gload_lds16(const ushort_t* g, ushort_t* l){
  __builtin_amdgcn_global_load_lds((const __attribute__((address_space(1))) unsigned int*)(const void*)g,
                                   (__attribute__((address_space(3))) unsigned int*)(void*)l, 16, 0, 0);
}

// ---------------- fused gray+laplacian+window-variance flags ----------------
__global__ __launch_bounds__(256) void k_flags2(const float* __restrict__ rgb,
                                                float* __restrict__ flags){
  __shared__ float sg[70][71];
  int bx = blockIdx.x & 7, by = (blockIdx.x >> 3) & 7, b = blockIdx.x >> 6;
  int wy0 = by*16, wx0 = bx*16;
  int y0 = 4*wy0 - 1, x0 = 4*wx0 - 1;
  const float* p = rgb + (size_t)b*3*262144;
  int tid = threadIdx.x;
  for (int i = tid; i < 70*70; i += 256){
    int r = i/70, cX = i%70;
    int y = y0 + r, x = x0 + cX;
    float v = 0.f;
    if (y>=0 && y<512 && x>=0 && x<512){
      int ii = y*512+x;
      v = 0.299f*p[ii] + 0.587f*p[ii+262144] + 0.114f*p[ii+524288];
      v = fminf(fmaxf(v*255.f, 0.f), 255.f);
    }
    sg[r][cX] = v;
  }
  __syncthreads();
  int wy = wy0 + (tid>>4), wx = wx0 + (tid&15);
  if (wy > 126 || wx > 126) return;
  int ry = 4*(tid>>4) + 1, rx = 4*(tid&15) + 1;
  float s1 = 0.f, s2 = 0.f;
  #pragma unroll
  for (int iy=0; iy<8; ++iy){
    int r = ry+iy;
    #pragma unroll
    for (int ix=0; ix<8; ++ix){
      int cX = rx+ix;
      float c = sg[r][cX];
      float lap = sg[r-1][cX] + sg[r+1][cX] + sg[r][cX-1] + sg[r][cX+1] - 4.f*c;
      s1 += lap; s2 += lap*lap;
    }
  }
  float var = (s2 - s1*s1*(1.f/64.f)) * (1.f/63.f);
  flags[(size_t)b*16129 + wy*127 + wx] = (var < 50.f) ? 1.f : 0.f;
}

// ---------------- all three downsampled mask pairs in one launch ----------------
__global__ void k_masks3(const float* __restrict__ flags, const float* __restrict__ depth,
                         float* __restrict__ ri0, float* __restrict__ di0,
                         float* __restrict__ ri1, float* __restrict__ di1,
                         float* __restrict__ ri2, float* __restrict__ di2){
  int idx = blockIdx.x*256 + threadIdx.x;
  const int n0 = 8*4096, n1 = 8*1024, n2 = 8*256;
  float* ri; float* di; int h, st, i2;
  if (idx < n0){ ri=ri0; di=di0; h=64; st=8;  i2=idx; }
  else if (idx < n0+n1){ ri=ri1; di=di1; h=32; st=16; i2=idx-n0; }
  else if (idx < n0+n1+n2){ ri=ri2; di=di2; h=16; st=32; i2=idx-n0-n1; }
  else return;
  int b = i2/(h*h), i = i2%(h*h);
  int y = (i/h)*st, x = (i%h)*st;
  const float* f = flags + (size_t)b*16129;
  int fy = y>>2, fx = x>>2;
  float v = f[fy*127+fx];
  if (y>0)         v = fmaxf(v, f[(fy-1)*127+fx]);
  if (x>0)         v = fmaxf(v, f[fy*127+fx-1]);
  if (y>0 && x>0)  v = fmaxf(v, f[(fy-1)*127+fx-1]);
  ri[i2] = v;
  const int IHW = 262144;
  di[i2] = (depth[(size_t)b*3*IHW + 2*IHW + (size_t)y*512 + x] <= 0.f) ? 1.f : 0.f;
}

// ---------------- weights -> bf16 [co][(ky*3+kx)*C+ci], LDS-staged transpose ----------------
template<int C>
__global__ __launch_bounds__(256) void k_wrd2(const float* __restrict__ w, ushort_t* __restrict__ outp){
  __shared__ float swp[9*C];
  int co = blockIdx.x, tid = threadIdx.x;
  const int n = 9*C;
  const float* src = w + (size_t)co*n;
  for (int i=tid;i<n;i+=256) swp[i]=src[i];
  __syncthreads();
  ushort_t* dst = outp + (size_t)co*n;
  for (int j=tid;j<n;j+=256)
    dst[j] = f2bf(swp[(j & (C-1))*9 + (j/C)]);
}

// ---------------- aux -> padded NHWC bf16 [dir][b][y+1][x+1][c], LDS transpose ----------------
// grid.x = B8*(H+2)*(C/64)*2 ; 256 threads
template<int C, int H, int W>
__global__ __launch_bounds__(256) void k_nhwc2(const float* __restrict__ rgbf,
                                               const float* __restrict__ depf,
                                               ushort_t* __restrict__ outp){
  const int W2 = W+2, H2 = H+2, CB = C/64;
  const int NHSZ = B8*H2*W2*C;
  __shared__ float st[64*66];
  int bi = blockIdx.x;
  int dir = bi & 1; bi >>= 1;
  int cb  = bi % CB; bi /= CB;
  int yy  = bi % H2;
  int b   = bi / H2;
  int tid = threadIdx.x;
  const float* in = (dir==0) ? depf : rgbf;     // aux = other modality
  ushort_t* outrow = outp + (size_t)dir*NHSZ + ((size_t)(b*H2 + yy)*W2)*C + cb*64;
  bool pad_row = (yy == 0) || (yy == H2-1);
  if (!pad_row){
    int y = yy-1;
    const float* src = in + ((size_t)(b*C + cb*64)*H + y)*W;
    for (int i=tid; i<64*W; i+=256){
      int c = i / W, x = i % W;
      st[x*66 + c] = src[(size_t)c*H*W + x];
    }
  }
  __syncthreads();
  for (int j=tid; j<W2*8; j+=256){
    int x = j >> 3, cc = (j & 7)*8;
    ushort_t tmp[8];
    if (pad_row || x == 0 || x == W2-1){
      #pragma unroll
      for (int q=0;q<8;++q) tmp[q]=0;
    } else {
      const float* sp = &st[(x-1)*66 + cc];
      float2 a0 = *(const float2*)(sp+0);
      float2 a1 = *(const float2*)(sp+2);
      float2 a2 = *(const float2*)(sp+4);
      float2 a3 = *(const float2*)(sp+6);
      tmp[0]=f2bf(a0.x); tmp[1]=f2bf(a0.y); tmp[2]=f2bf(a1.x); tmp[3]=f2bf(a1.y);
      tmp[4]=f2bf(a2.x); tmp[5]=f2bf(a2.y); tmp[6]=f2bf(a3.x); tmp[7]=f2bf(a3.y);
    }
    *(bf16x8*)&outrow[(size_t)x*C + cc] = *(bf16x8*)tmp;
  }
}

// ---------------- implicit-GEMM conv, dual-dir + split-K, 1024 WGs ----------------
// G layout: [dir*KS+kz][C][N]
template<int C, int H, int W, int KS>
__global__ __launch_bounds__(256)
void k_gemm_conv(const ushort_t* __restrict__ Aw, const ushort_t* __restrict__ nh,
                 float* __restrict__ outp){
  const int K9 = 9*C;
  const int HW = H*W;
  const int N  = B8*HW;
  const int H2 = H+2, W2 = W+2;
  const int NT_N = N/128, NT_M = C/128;
  const int KCT = (K9/64)/KS;
  const int NHSZ = B8*H2*W2*C;
  __shared__ ushort_t sA[128*64];
  __shared__ ushort_t sB[128*64];
  int t = threadIdx.x;

  const int nwg = 2*KS*NT_M*NT_N;      // = 1024 for all scales
  int bid = blockIdx.x;
  int swz = (bid & 7)*(nwg >> 3) + (bid >> 3);
  int n_t = swz % NT_N; int tmp = swz / NT_N;
  int m_t = tmp % NT_M; int kz2 = tmp / NT_M;   // kz2 = dir*KS + kz
  int dir = kz2 / KS,   kz  = kz2 % KS;

  const ushort_t* nhd = nh + (size_t)dir*NHSZ;
  int m0 = m_t*128, n0 = n_t*128;
  int l = t & 63, wv = t >> 6;
  int wm = wv >> 1, wn = wv & 1;

  int trow = t >> 3;
  int k8   = (t & 7) * 8;
  long long aoff[4], boff[4];
  #pragma unroll
  for (int i=0;i<4;++i){
    int row = trow + 32*i;
    aoff[i] = (long long)(m0 + row)*K9 + k8;
    int n = n0 + row;
    int b = n / HW, r = n % HW;
    int y = r / W,  x = r % W;
    boff[i] = ((long long)(b*H2 + y + 1)*W2 + (x + 1))*(long long)C + k8;
  }
  f32x4 acc[4][4];
  #pragma unroll
  for (int i=0;i<4;++i)
    #pragma unroll
    for (int j=0;j<4;++j) acc[i][j] = (f32x4){0.f,0.f,0.f,0.f};

  int lrow = l & 15, lk = (l >> 4)*8;

  int kc0 = kz*KCT, kc1 = kc0 + KCT;
  for (int kc = kc0; kc < kc1; ++kc){
    int off = kc << 6;
    int kq  = off / C;
    int c0  = off & (C-1);
    int dy = kq/3 - 1, dx = kq%3 - 1;
    long long duvC = (long long)(dy*W2 + dx)*C;
    #pragma unroll
    for (int i=0;i<4;++i){
      gload_lds16(Aw  + aoff[i] + off,       &sA[0] + 8*t + 2048*i);
      gload_lds16(nhd + boff[i] + duvC + c0, &sB[0] + 8*t + 2048*i);
    }
    __syncthreads();
    bf16x8 af[4][2], bfr[4][2];
    #pragma unroll
    for (int mi=0;mi<4;++mi)
      #pragma unroll
      for (int kk=0;kk<2;++kk){
        af[mi][kk]  = *(const bf16x8*)&sA[(wm*64 + mi*16 + lrow)*64 + kk*32 + lk];
        bfr[mi][kk] = *(const bf16x8*)&sB[(wn*64 + mi*16 + lrow)*64 + kk*32 + lk];
      }
    #pragma unroll
    for (int kk=0;kk<2;++kk)
      #pragma unroll
      for (int mi=0;mi<4;++mi)
        #pragma unroll
        for (int ni=0;ni<4;++ni)
          acc[mi][ni] = __builtin_amdgcn_mfma_f32_16x16x32_bf16(af[mi][kk], bfr[ni][kk], acc[mi][ni], 0,0,0);
    __syncthreads();
  }
  float* po = outp + (size_t)kz2*C*N;
  int orow = m0 + wm*64 + (l>>4)*4;
  int ocol = n0 + wn*64 + (l&15);
  #pragma unroll
  for (int mi=0;mi<4;++mi)
    #pragma unroll
    for (int ni=0;ni<4;++ni)
      #pragma unroll
      for (int r=0;r<4;++r)
        po[(size_t)(orow + mi*16 + r)*N + ocol + ni*16] = acc[mi][ni][r];
}

// ---------------- split-K reduce (into kz=0 slot, in place) + BN stats; dual-dir ----------------
__global__ __launch_bounds__(256)
void k_redbn(float* __restrict__ G, const float* __restrict__ g,
             const float* __restrict__ bb, float* __restrict__ alpha,
             float* __restrict__ beta, int N, int ks, int C){
  int c = blockIdx.x, dir = blockIdx.y, tid = threadIdx.x;
  size_t MN = (size_t)C*N;
  float* p0 = G + (size_t)dir*ks*MN + (size_t)c*N;
  float s1 = 0.f, s2 = 0.f;
  for (int i = tid*4; i < N; i += 1024){
    float4 v = *(const float4*)(p0 + i);
    for (int kz=1; kz<ks; ++kz){
      const float4 w = *(const float4*)(p0 + (size_t)kz*MN + i);
      v.x += w.x; v.y += w.y; v.z += w.z; v.w += w.w;
    }
    if (ks > 1) *(float4*)(p0 + i) = v;
    s1 += v.x + v.y + v.z + v.w;
    s2 += v.x*v.x + v.y*v.y + v.z*v.z + v.w*v.w;
  }
  __shared__ float sb1[4], sb2[4];
  #pragma unroll
  for (int off=32; off; off>>=1){ s1 += __shfl_down(s1,off); s2 += __shfl_down(s2,off); }
  int wid = tid>>6;
  if ((tid&63)==0){ sb1[wid]=s1; sb2[wid]=s2; }
  __syncthreads();
  if (tid==0){
    s1 = sb1[0]+sb1[1]+sb1[2]+sb1[3];
    s2 = sb2[0]+sb2[1]+sb2[2]+sb2[3];
    float Nf = (float)N;
    float mean = s1/Nf;
    float var  = s2/Nf - mean*mean;
    float a = g[c] / sqrtf(var + 1e-5f);
    alpha[dir*C + c] = a;
    beta[dir*C + c]  = bb[c] - mean*a;
  }
}

// ---------------- per-position channel mean/max, dual-dir ----------------
template<int NS>
__global__ void k_spstats(const float* __restrict__ rgbf, const float* __restrict__ depf,
                          float* __restrict__ spmean, float* __restrict__ spmax,
                          int C, int HW){
  int dir = blockIdx.y;
  const float* main_ = (dir==0) ? rgbf : depf;
  int tid = threadIdx.x;
  int slice = tid % NS;
  int pos = blockIdx.x*(256/NS) + tid/NS;
  int b = pos / HW, i = pos % HW;
  const float* p = main_ + (size_t)b*C*HW + i;
  float sum = 0.f, mx = -INFINITY;
  for (int c=slice; c<C; c+=NS){
    float v = p[(size_t)c*HW];
    sum += v; mx = fmaxf(mx, v);
  }
  #pragma unroll
  for (int off=NS/2; off; off>>=1){
    sum += __shfl_xor(sum, off);
    mx = fmaxf(mx, __shfl_xor(mx, off));
  }
  if (slice==0){
    size_t o = (size_t)dir*B8*HW + pos;
    spmean[o] = sum/C; spmax[o] = mx;
  }
}

// ---------------- spatial attention, dual-dir ----------------
__global__ void k_sw(const float* __restrict__ spmean, const float* __restrict__ spmax,
                     const float* __restrict__ sa, float* __restrict__ sw,
                     int H, int W){
  __shared__ float s_sa[196];
  int tid = threadIdx.x;
  if (tid < 196) s_sa[tid] = sa[tid];
  __syncthreads();
  int HW = H*W;
  int dir = blockIdx.y;
  int gpos = blockIdx.x*256 + tid;
  if (gpos >= B8*HW) return;
  int b = gpos/HW, i = gpos%HW;
  int y = i/W, x = i%W;
  float inv_w = 2.f/(float)(W-1), inv_h = 2.f/(float)(H-1);
  const float* pm = spmean + (size_t)dir*B8*HW + (size_t)b*HW;
  const float* px = spmax  + (size_t)dir*B8*HW + (size_t)b*HW;
  float acc = 0.f;
  for (int ky=0;ky<7;++ky){
    int yy = y+ky-3;
    if (yy<0 || yy>=H) continue;
    float ysv = -1.f + yy*inv_h;
    for (int kx=0;kx<7;++kx){
      int xx = x+kx-3;
      if (xx<0 || xx>=W) continue;
      float xsv = -1.f + xx*inv_w;
      int kk = ky*7+kx;
      acc += s_sa[kk]*pm[yy*W+xx] + s_sa[49+kk]*px[yy*W+xx]
           + s_sa[98+kk]*xsv + s_sa[147+kk]*ysv;
    }
  }
  sw[(size_t)dir*B8*HW + gpos] = sigmoidf_(acc);
}

// ---------------- global average pool, dual-dir ----------------
__global__ void k_gap(const float* __restrict__ rgbf, const float* __restrict__ depf,
                      float* __restrict__ gap, int C, int HW){
  int dir = blockIdx.y;
  const float* main_ = (dir==0) ? rgbf : depf;
  const float* p = main_ + (size_t)blockIdx.x*HW;
  float s = 0.f;
  for (int i=threadIdx.x; i<HW; i+=64) s += p[i];
  #pragma unroll
  for (int off=32; off; off>>=1) s += __shfl_down(s, off);
  if (threadIdx.x==0) gap[(size_t)dir*gridDim.x + blockIdx.x] = s/(float)HW;
}

// ---------------- channel attention MLP, dual-dir ----------------
__global__ void k_mlp(const float* __restrict__ gap, const float* __restrict__ w1,
                      const float* __restrict__ w2, float* __restrict__ cw,
                      int C, int R){
  int b = blockIdx.x, dir = blockIdx.y;
  int tid = threadIdx.x;
  __shared__ float sg[1024];
  __shared__ float sh[64];
  const float* gp = gap + (size_t)dir*B8*C + (size_t)b*C;
  for (int c=tid;c<C;c+=256) sg[c]=gp[c];
  __syncthreads();
  int r = tid>>2, q = tid&3;
  if (r < R){
    float s = 0.f;
    for (int c=q;c<C;c+=4) s += w1[(size_t)r*C + c]*sg[c];
    s += __shfl_xor(s,1); s += __shfl_xor(s,2);
    if (q==0) sh[r] = fmaxf(s, 0.f);
  }
  __syncthreads();
  for (int c2=tid; c2<C; c2+=256){
    float s = 0.f;
    for (int rr=0;rr<R;++rr) s += w2[(size_t)c2*R + rr]*sh[rr];
    cw[(size_t)dir*B8*C + (size_t)b*C + c2] = sigmoidf_(s);
  }
}

// ---------------- final masked compose, dual-dir ----------------
__global__ void k_final(const float* __restrict__ rgbf, const float* __restrict__ depf,
                        const float* __restrict__ G,
                        const float* __restrict__ alpha, const float* __restrict__ beta,
                        const float* __restrict__ sw, const float* __restrict__ cw,
                        const float* __restrict__ ri, const float* __restrict__ di,
                        float* __restrict__ out_r, float* __restrict__ out_d,
                        int C, int HW, int ks){
  int dir = blockIdx.y;
  const float* main_ = (dir==0) ? rgbf : depf;
  const float* mask  = (dir==0) ? ri : di;
  float* out = (dir==0) ? out_r : out_d;
  size_t idx = (size_t)blockIdx.x*256 + threadIdx.x;
  size_t Nt = (size_t)B8*C*HW;
  if (idx >= Nt) return;
  int N = B8*HW;
  const float* conv = G + (size_t)dir*ks*C*N;
  int i = (int)(idx % HW);
  size_t t = idx / HW;
  int c = (int)(t % C);
  int b = (int)(t / C);
  float m = mask[(size_t)b*HW + i];
  float res;
  if (m > 0.5f){
    float cv = conv[(size_t)c*N + (size_t)b*HW + i];
    float at = fmaxf(alpha[dir*C + c]*cv + beta[dir*C + c], 0.f);
    res = 2.f*at*sw[(size_t)dir*B8*HW + (size_t)b*HW + i]*cw[(size_t)dir*B8*C + (size_t)b*C + c];
  } else {
    res = main_[idx];
  }
  out[idx] = res;
}

extern "C" void kernel_launch(void* const* d_in, const int* in_sizes, int n_in,
                              void* d_out, int out_size, void* d_ws, size_t ws_size,
                              hipStream_t stream){
  (void)in_sizes; (void)n_in; (void)out_size; (void)ws_size;
  const int B = B8;
  const float* rgb_feat[3] = {(const float*)d_in[0], (const float*)d_in[2], (const float*)d_in[4]};
  const float* dep_feat[3] = {(const float*)d_in[1], (const float*)d_in[3], (const float*)d_in[5]};
  const float* rgb_img = (const float*)d_in[6];
  const float* dep_img = (const float*)d_in[7];

  const int Cs[3]  = {256, 512, 1024};
  const int hs[3]  = {64, 32, 16};
  const int HWs[3] = {64*64, 32*32, 16*16};
  const int KSs[3] = {1, 2, 4};

  float* ws = (float*)d_ws;
  // layout: [G: 16,777,216 floats (flags aliases base)] [ri/di: 86,016] [scratch: 9,216,016]
  float* G  = ws;
  float* flags = G;                       // dead before gemm writes G
  float* rdbase = ws + 16777216;
  float* ri[3]; float* di[3];
  {
    size_t o = 0;
    for (int s=0;s<3;++s){
      ri[s] = rdbase + o; o += (size_t)B*hs[s]*hs[s];
      di[s] = rdbase + o; o += (size_t)B*hs[s]*hs[s];
    }
  }
  float* SB = rdbase + 86016;             // scratch base (nhbf | wbf), smalls alias nhbf

  // transient smalls (alias nhbf region; only live after gemm of their scale)
  float* alphab = SB + 0;
  float* betab  = SB + 2048;
  float* spmean = SB + 4096;
  float* spmax  = SB + 69632;
  float* swb    = SB + 135168;
  float* gapb   = SB + 200704;
  float* cwb    = SB + 217088;

  // stage A: masks
  k_flags2<<<512, 256, 0, stream>>>(rgb_img, flags);
  k_masks3<<<168, 256, 0, stream>>>(flags, dep_img, ri[0], di[0], ri[1], di[1], ri[2], di[2]);

  const size_t outoff_r[3] = {0,         8388608u,  12582912u};
  const size_t outoff_d[3] = {14680064u, 23068672u, 27262976u};
  float* outp = (float*)d_out;

  for (int s=0;s<3;++s){
    const float* ftw = (const float*)d_in[8 +6*s];
    const float* bng = (const float*)d_in[9 +6*s];
    const float* bnb = (const float*)d_in[10+6*s];
    const float* saw = (const float*)d_in[11+6*s];
    const float* ca1 = (const float*)d_in[12+6*s];
    const float* ca2 = (const float*)d_in[13+6*s];
    int C = Cs[s], HW = HWs[s], h = hs[s];
    int R = C/16;
    int BHW = B*HW;
    int ks = KSs[s];

    size_t nh_f = (size_t)B*(h+2)*(h+2)*C;          // per-dir ushorts = 2*nh_f shorts -> nh_f floats total for 2 dirs
    ushort_t* nhbf = (ushort_t*)SB;                  // 2 dirs, [dir][b][y][x][c]
    ushort_t* wbf  = (ushort_t*)(SB + nh_f);

    // weights reorder (shared by both dirs)
    if (s==0) k_wrd2<256> <<<256,  256, 0, stream>>>(ftw, wbf);
    if (s==1) k_wrd2<512> <<<512,  256, 0, stream>>>(ftw, wbf);
    if (s==2) k_wrd2<1024><<<1024, 256, 0, stream>>>(ftw, wbf);

    // aux -> padded NHWC bf16, both dirs
    {
      unsigned nb = (unsigned)(B*(h+2)*(C/64)*2);
      if (s==0) k_nhwc2<256, 64,64><<<nb, 256, 0, stream>>>(rgb_feat[s], dep_feat[s], nhbf);
      if (s==1) k_nhwc2<512, 32,32><<<nb, 256, 0, stream>>>(rgb_feat[s], dep_feat[s], nhbf);
      if (s==2) k_nhwc2<1024,16,16><<<nb, 256, 0, stream>>>(rgb_feat[s], dep_feat[s], nhbf);
    }

    // implicit GEMM conv, dual-dir + split-K, 1024 WGs
    if (s==0) k_gemm_conv<256, 64,64,1><<<1024, 256, 0, stream>>>(wbf, nhbf, G);
    if (s==1) k_gemm_conv<512, 32,32,2><<<1024, 256, 0, stream>>>(wbf, nhbf, G);
    if (s==2) k_gemm_conv<1024,16,16,4><<<1024, 256, 0, stream>>>(wbf, nhbf, G);

    // reduce + BN stats (both dirs)
    k_redbn<<<dim3(C,2), 256, 0, stream>>>(G, bng, bnb, alphab, betab, BHW, ks, C);

    if (s==0) k_spstats<4> <<<dim3(512,2), 256, 0, stream>>>(rgb_feat[s], dep_feat[s], spmean, spmax, C, HW);
    if (s==1) k_spstats<8> <<<dim3(256,2), 256, 0, stream>>>(rgb_feat[s], dep_feat[s], spmean, spmax, C, HW);
    if (s==2) k_spstats<32><<<dim3(256,2), 256, 0, stream>>>(rgb_feat[s], dep_feat[s], spmean, spmax, C, HW);

    k_sw <<<dim3((B*HW+255)/256,2), 256, 0, stream>>>(spmean, spmax, saw, swb, h, h);
    k_gap<<<dim3(B*C,2), 64, 0, stream>>>(rgb_feat[s], dep_feat[s], gapb, C, HW);
    k_mlp<<<dim3(B,2), 256, 0, stream>>>(gapb, ca1, ca2, cwb, C, R);

    size_t Nt = (size_t)B*C*HW;
    k_final<<<dim3((unsigned)((Nt+255)/256),2), 256, 0, stream>>>(
        rgb_feat[s], dep_feat[s], G, alphab, betab, swb, cwb,
        ri[s], di[s], outp + outoff_r[s], outp + outoff_d[s], C, HW, ks);
  }
}